// Round 9
// baseline (311.227 us; speedup 1.0000x reference)
//
#include <hip/hip_runtime.h>

typedef unsigned short ushort_t;
typedef unsigned int uint_t;

#define NN 20000
#define EE 320000
#define CC 32
#define NEL 10
#define GG 64
#define TTT 1000
#define NBB 8
#define HIDD 64
#define EPB 256         // edges per block in k_rw_mfma (EE = 1250*256 exactly)
#define NTILE (EE / 16) // 20000 16-slot tiles

typedef __attribute__((ext_vector_type(8))) short bf16x8;
typedef __attribute__((ext_vector_type(4))) float f32x4;

__device__ __forceinline__ float bits2f(uint_t b) { union { uint_t u; float f; } v; v.u = b; return v.f; }
__device__ __forceinline__ ushort_t f2b(float f) {
  union { float f; uint_t u; } v; v.f = f;
  uint_t r = (v.u + 0x7fffu + ((v.u >> 16) & 1u)) >> 16;
  return (ushort_t)r;
}
// single-instruction packed f32->bf16 (RNE, same as f2b) [gfx950 v_cvt_pk_bf16_f32]
__device__ __forceinline__ uint_t pk(float a, float b) {
  uint_t r;
  asm("v_cvt_pk_bf16_f32 %0, %1, %2" : "=v"(r) : "v"(a), "v"(b));
  return r;
}
__device__ __forceinline__ float lo16(uint_t u) { return bits2f(u << 16); }
__device__ __forceinline__ float hi16(uint_t u) { return bits2f(u & 0xffff0000u); }
// fast reciprocal (v_rcp_f32, ~2^-22 rel err) -- outputs here are bf16 (2^-8)
__device__ __forceinline__ float frcp(float x) { return __builtin_amdgcn_rcpf(x); }

// ---------------- K1: node prep (zeroes deg) + weight packing (merged) -------
// blocks [0,79): node prep; blocks [79,175): pack W2^T / Wmix to bf16 global
__global__ __launch_bounds__(256) void k_prep(
    const float* __restrict__ positions, const float* __restrict__ node_attrs,
    const float* __restrict__ eps, const float* __restrict__ alpha_bar,
    const float* __restrict__ W_embed, const float* __restrict__ W_sc,
    const float* __restrict__ W_r2, const float* __restrict__ W_mix,
    const int* __restrict__ batch, const int* __restrict__ tarr,
    float* __restrict__ pos_noisy, float* __restrict__ scalA,
    float* __restrict__ sc_skip, float* __restrict__ pred, int* __restrict__ deg,
    ushort_t* __restrict__ w2tg, ushort_t* __restrict__ wmixb)
{
  if (blockIdx.x >= 79) {   // ---- weight-pack role ----
    int idx = (blockIdx.x - 79) * 256 + threadIdx.x;   // 96*256 = 24576
    if (idx < 16384) {
      int l = idx >> 13, r = idx & 8191;
      int n = r >> 6, k = r & 63;
      w2tg[idx] = f2b(W_r2[l * 8192 + k * 128 + n]);
    } else {
      int r = idx - 16384;
      int l = r >> 12, r2 = r & 4095;
      int col = r2 >> 5, ch = r2 & 31;
      int lq = col >> 5, d = col & 31;
      wmixb[r] = f2b(W_mix[l * 4096 + lq * 1024 + ch * 32 + d]);
    }
    return;
  }
  int n = blockIdx.x * 256 + threadIdx.x;
  if (n >= NN) return;
  deg[n] = 0;
  int g = batch[n];
  int tn = tarr[g];
  float ab = alpha_bar[tn];
  float sa = sqrtf(ab), sb = sqrtf(fmaxf(1.0f - ab, 0.0f));
#pragma unroll
  for (int j = 0; j < 3; ++j)
    pos_noisy[n * 3 + j] = sa * positions[n * 3 + j] + sb * eps[n * 13 + 10 + j];
  float an[10];
#pragma unroll
  for (int j = 0; j < 10; ++j)
    an[j] = sa * 0.25f * node_attrs[n * 10 + j] + sb * eps[n * 13 + j];
  float tf = (float)tn * (1.0f / (float)TTT);
  for (int d = 0; d < CC; ++d) {
    float h = tf * W_embed[10 * CC + d];
    float sk = 0.0f;
#pragma unroll
    for (int j = 0; j < 10; ++j) {
      h = fmaf(an[j], W_embed[j * CC + d], h);
      sk = fmaf(an[j], W_sc[j * CC + d], sk);
    }
    scalA[n * CC + d] = h;
    sc_skip[n * CC + d] = sk;
  }
#pragma unroll
  for (int j = 0; j < 13; ++j) pred[n * 13 + j] = 0.0f;
}

// ---------------- K2a: receiver histogram ----------------
__global__ __launch_bounds__(256) void k_edge_deg(const int* __restrict__ ei,
    int* __restrict__ deg)
{
  int e = blockIdx.x * 256 + threadIdx.x;  // EE = 1250*256 exactly
  atomicAdd(&deg[ei[EE + e]], 1);
}

// ---------------- K3: exclusive scan deg -> offs, cursor; zero loss accum ----
__global__ __launch_bounds__(1024) void k_scan(const int* __restrict__ deg,
    int* __restrict__ offs, int* __restrict__ cursor,
    float* __restrict__ lnum, float* __restrict__ lcnt)
{
  __shared__ int wsums[16];
  __shared__ int woffs[16];
  int tid = threadIdx.x, lane = tid & 63, wv = tid >> 6;
  if (tid < GG) { lnum[tid] = 0.0f; lcnt[tid] = 0.0f; }
  int base = tid * 20;
  int loc[20];
  int s = 0;
#pragma unroll
  for (int j = 0; j < 20; ++j) {
    int idx = base + j;
    int v = (idx < NN) ? deg[idx] : 0;
    loc[j] = s; s += v;
  }
  int inc = s;
  for (int o = 1; o < 64; o <<= 1) {
    int v = __shfl_up(inc, o, 64);
    if (lane >= o) inc += v;
  }
  if (lane == 63) wsums[wv] = inc;
  __syncthreads();
  if (wv == 0 && lane < 16) {
    int v = wsums[lane];
    int i2 = v;
    for (int o = 1; o < 16; o <<= 1) {
      int vv = __shfl_up(i2, o, 16);
      if (lane >= o) i2 += vv;
    }
    woffs[lane] = i2 - v;
  }
  __syncthreads();
  int texcl = woffs[wv] + (inc - s);
#pragma unroll
  for (int j = 0; j < 20; ++j) {
    int idx = base + j;
    if (idx < NN) { int v = texcl + loc[j]; offs[idx] = v; cursor[idx] = v; }
  }
  if (tid == 1023) offs[NN] = EE;
}

// ---------------- K4: edge geometry; Y written DIRECTLY transposed to YT -----
// YT[tile][k][el] (el = slot & 15): 16 x 2B scatter stores per edge replaces
// the Ys buffer + separate k_ytr transpose pass entirely.
__global__ __launch_bounds__(256) void k_edge2(
    const float* __restrict__ pos_noisy, const float* __restrict__ shifts,
    const int* __restrict__ ei, int* __restrict__ cursor,
    ushort_t* __restrict__ YT, ushort_t* __restrict__ efs, int* __restrict__ snds)
{
  int e = blockIdx.x * 256 + threadIdx.x;  // EE exact
  int snd = ei[e], rcv = ei[EE + e];
  float vx = pos_noisy[rcv * 3 + 0] - pos_noisy[snd * 3 + 0] + shifts[e * 3 + 0];
  float vy = pos_noisy[rcv * 3 + 1] - pos_noisy[snd * 3 + 1] + shifts[e * 3 + 1];
  float vz = pos_noisy[rcv * 3 + 2] - pos_noisy[snd * 3 + 2] + shifts[e * 3 + 2];
  float r2 = vx * vx + vy * vy + vz * vz + 1e-12f;
  float r = sqrtf(r2);
  float inv = frcp(r);            // feeds bf16 outputs only
  float x = vx * inv, y = vy * inv, z = vz * inv;

  const float s3 = 1.7320508075688772f, s15 = 3.872983346207417f, s5 = 2.23606797749979f;
  const float s105 = 10.246950765959598f, s7 = 2.6457513110645907f;
  const float s35_8 = 2.091650066335189f, s21_8 = 1.6201851746019651f;
  float yv[16];
  yv[0] = 1.0f;
  yv[1] = s3 * x; yv[2] = s3 * y; yv[3] = s3 * z;
  yv[4] = s15 * x * y;
  yv[5] = s15 * y * z;
  yv[6] = 0.5f * s5 * (3.0f * z * z - 1.0f);
  yv[7] = s15 * x * z;
  yv[8] = 0.5f * s15 * (x * x - y * y);
  yv[9] = s35_8 * y * (3.0f * x * x - y * y);
  yv[10] = s105 * x * y * z;
  yv[11] = s21_8 * y * (5.0f * z * z - 1.0f);
  yv[12] = 0.5f * s7 * (5.0f * z * z * z - 3.0f * z);
  yv[13] = s21_8 * x * (5.0f * z * z - 1.0f);
  yv[14] = 0.5f * s105 * z * (x * x - y * y);
  yv[15] = s35_8 * x * (x * x - 3.0f * y * y);

  // radial embed: sqrt(2/5) * sin(n*pi*rc/5)/rc * poly_cutoff(r/5)
  float rc = fmaxf(r, 1e-9f);
  float pref = 0.6324555320336759f * frcp(rc);   // bf16 output -> fast rcp ok
  float th = 0.6283185307179586f * rc;
  float s1 = __sinf(th), c1 = __cosf(th);
  float xr = r * 0.2f;
  float fcut = 0.0f;
  if (xr < 1.0f) {
    float x2 = xr * xr, x3 = x2 * xr;
    float x6 = x3 * x3, x7 = x6 * xr, x8 = x7 * xr;
    fcut = 1.0f - 28.0f * x6 + 48.0f * x7 - 21.0f * x8;
  }
  float efv[8];
  float sp = 0.0f, scur = s1, c2 = 2.0f * c1;
#pragma unroll
  for (int b = 0; b < 8; ++b) {
    efv[b] = pref * scur * fcut;
    float nx = c2 * scur - sp;   // sin((n+1)th) = 2cos(th)sin(n th) - sin((n-1)th)
    sp = scur; scur = nx;
  }

  int slot = atomicAdd(&cursor[rcv], 1);
  snds[slot] = snd;
  // direct transposed Y store: YT[tile][k][el], el = slot&15
  {
    int tile = slot >> 4, el = slot & 15;
    ushort_t* yt = YT + (size_t)tile * 256 + el;
#pragma unroll
    for (int p = 0; p < 8; ++p) {
      uint_t u = pk(yv[2 * p], yv[2 * p + 1]);
      yt[(2 * p) * 16]     = (ushort_t)(u & 0xffffu);
      yt[(2 * p + 1) * 16] = (ushort_t)(u >> 16);     // global_store_short_d16_hi
    }
  }
  ((uint4*)efs)[slot] = make_uint4(pk(efv[0], efv[1]), pk(efv[2], efv[3]),
                                   pk(efv[4], efv[5]), pk(efv[6], efv[7]));
}

// ---------------- K5: edge radial MLP via MFMA, ss folded, TRANSPOSED store --
// W2^T comes from global bf16 (w2tg) -> only h1 lives in LDS (36.9 KB, 4 blk/CU)
__global__ __launch_bounds__(256) void k_rw_mfma(
    const ushort_t* __restrict__ efs, const float* __restrict__ W_r1,
    const ushort_t* __restrict__ w2tg, const int* __restrict__ snds,
    const float* __restrict__ scal_in, ushort_t* __restrict__ rwT, int layer)
{
  __shared__ __align__(16) ushort_t h1[EPB][72];    // silu(ef@W1) bf16, padded
  int tid = threadIdx.x;
  const float* W1g = W_r1 + layer * NBB * HIDD;
  const ushort_t* w2l = w2tg + layer * (HIDD * 128);
  // h1 for this thread's edge (one edge per thread)
  {
    int e = blockIdx.x * EPB + tid;
    uint4 q = ((const uint4*)efs)[e];
    float efr[8] = {lo16(q.x), hi16(q.x), lo16(q.y), hi16(q.y),
                    lo16(q.z), hi16(q.z), lo16(q.w), hi16(q.w)};
    for (int hc = 0; hc < 8; ++hc) {
      float v[8];
#pragma unroll
      for (int hh = 0; hh < 8; ++hh) {
        int h = hc * 8 + hh;
        float t = 0.0f;
#pragma unroll
        for (int b = 0; b < 8; ++b) t = fmaf(efr[b], W1g[b * HIDD + h], t);
        v[hh] = t * frcp(1.0f + __expf(-t));   // silu, fast rcp (bf16 out)
      }
      *(uint4*)&h1[tid][hc * 8] = make_uint4(pk(v[0], v[1]), pk(v[2], v[3]),
                                             pk(v[4], v[5]), pk(v[6], v[7]));
    }
  }
  __builtin_amdgcn_wave_barrier();   // h1 rows are wave-private (64 rows per wave)
  int w = tid >> 6, lane = tid & 63;
  int c = lane & 15, quad = lane >> 4;
  // all 16 B-fragments (8 n-tiles x 2 k-tiles) from global bf16 (L1-hot, hoisted)
  bf16x8 bfr[16];
#pragma unroll
  for (int nt = 0; nt < 8; ++nt)
#pragma unroll
    for (int kt = 0; kt < 2; ++kt)
      bfr[nt * 2 + kt] = *(const bf16x8*)&w2l[(nt * 16 + c) * 64 + kt * 32 + quad * 8];
  int mb0 = w * 64;   // this wave covers 64 edges = 4 m-tiles
#pragma unroll
  for (int mt = 0; mt < 4; ++mt) {
    int mbase = mb0 + mt * 16;
    bf16x8 a0 = *(const bf16x8*)&h1[mbase + c][quad * 8];
    bf16x8 a1 = *(const bf16x8*)&h1[mbase + c][32 + quad * 8];
    size_t erow = (size_t)blockIdx.x * EPB + mbase + quad * 4;
    int4 sn = *(const int4*)&snds[erow];     // 4 consecutive edges' senders
    const float* sb0 = scal_in + (size_t)sn.x * CC;
    const float* sb1 = scal_in + (size_t)sn.y * CC;
    const float* sb2 = scal_in + (size_t)sn.z * CC;
    const float* sb3 = scal_in + (size_t)sn.w * CC;
    int tile = blockIdx.x * 16 + w * 4 + mt;  // global 16-slot tile index
#pragma unroll
    for (int nt = 0; nt < 8; ++nt) {
      f32x4 acc = {0.0f, 0.0f, 0.0f, 0.0f};
      acc = __builtin_amdgcn_mfma_f32_16x16x32_bf16(a0, bfr[nt * 2 + 0], acc, 0, 0, 0);
      acc = __builtin_amdgcn_mfma_f32_16x16x32_bf16(a1, bfr[nt * 2 + 1], acc, 0, 0, 0);
      int col = nt * 16 + c;
      int cc = col >> 2;                     // channel = col/4 (col = 4c+l)
      // C layout: acc[j] is edge (quad*4+j) of this tile, fixed col.
      uint2 st;
      st.x = pk(acc[0] * sb0[cc], acc[1] * sb1[cc]);
      st.y = pk(acc[2] * sb2[cc], acc[3] * sb3[cc]);
      *(uint2*)(rwT + (size_t)tile * 2048 + (size_t)col * 16 + quad * 4) = st;
    }
  }
}

// ---------------- K6: MFMA segment-aggregate + MFMA mix + poly + readout -----
// LDS: single aliased buffer lbuf holds agg[ch][k] then feats[d][k] (the agg
// data is fully consumed by the mix A-frag reads before feats is written;
// per-wave LDS is in-order and the wave executes in lockstep -> no race).
__global__ __launch_bounds__(256) void k_layer(
    const ushort_t* __restrict__ YT, const ushort_t* __restrict__ rwT,
    float* __restrict__ scal_out,
    const int* __restrict__ offs,
    const ushort_t* __restrict__ wmixb, const float* __restrict__ W_prod,
    const float* __restrict__ W_ro_s, const float* __restrict__ W_ro_v,
    const float* __restrict__ sc_skip, float* __restrict__ pred, int layer)
{
  __shared__ float lbuf[4][CC][17];    // 8.7 KB (aliased agg/feats), pad 17
  __shared__ float lf[4][CC][4];       // 2 KB
  int w = threadIdx.x >> 6, lane = threadIdx.x & 63;
  int n = blockIdx.x * 4 + w;        // NN = 5000*4 exactly
  int c = lane & 15, quad = lane >> 4;
  int i0 = offs[n], i1 = offs[n + 1];
  int t0 = i0 >> 4, t1 = (i1 + 15) >> 4;   // tiles overlapping this node
  int tsel = quad >> 1, half8 = quad & 1;
  f32x4 acc[8];
#pragma unroll
  for (int mt = 0; mt < 8; ++mt) acc[mt] = (f32x4){0.0f, 0.0f, 0.0f, 0.0f};

  for (int t = t0; t < t1; t += 2) {       // K = 32 edges per step (2 tiles)
    int ta = t + tsel;                      // quad pair 0/1 -> tile t, 2/3 -> t+1
    bf16x8 a[8];
    bf16x8 b;
    int sbase = ta * 16 + half8 * 8;
    // this quad-half contributes iff its 8-slot range intersects the segment
    bool av = (sbase < i1) && (sbase + 8 > i0) && (ta < t1);
    if (av) {
      const bf16x8* ap = (const bf16x8*)rwT + (size_t)ta * 256 + c * 2 + half8;
#pragma unroll
      for (int mt = 0; mt < 8; ++mt) a[mt] = ap[mt * 32];
      b = ((const bf16x8*)YT)[(size_t)ta * 32 + c * 2 + half8];
      if (sbase < i0 || sbase + 8 > i1) {
#pragma unroll
        for (int j = 0; j < 8; ++j) {
          int s = sbase + j;
          if (s < i0 || s >= i1) b[j] = 0;   // zero Y outside segment -> 0 contrib
        }
      }
    } else {
#pragma unroll
      for (int mt = 0; mt < 8; ++mt) a[mt] = (bf16x8){0, 0, 0, 0, 0, 0, 0, 0};
      b = (bf16x8){0, 0, 0, 0, 0, 0, 0, 0};
    }
#pragma unroll
    for (int mt = 0; mt < 8; ++mt)
      acc[mt] = __builtin_amdgcn_mfma_f32_16x16x32_bf16(a[mt], b, acc[mt], 0, 0, 0);
  }

  // C layout: acc[mt][j] = agg_full[row = mt*16 + quad*4 + j][k = c]
  //   -> channel = mt*4 + quad, kk = j; select j = L_OF_LM[c]
  int lc = (c >= 1) + (c >= 4) + (c >= 9);
  const float inva = 1.0f / 16.0f;
#pragma unroll
  for (int mt = 0; mt < 8; ++mt) {
    float v = (lc == 0) ? acc[mt][0] : (lc == 1) ? acc[mt][1]
            : (lc == 2) ? acc[mt][2] : acc[mt][3];
    lbuf[w][mt * 4 + quad][c] = v * inva;    // agg[ch][k]
  }
  __builtin_amdgcn_wave_barrier();

  // ---- mix via MFMA: out[k][lq*32+d] = sum_ch agg[ch][k] * Wm[lq][ch][d] ----
  float av2[8];
#pragma unroll
  for (int j = 0; j < 8; ++j) av2[j] = lbuf[w][quad * 8 + j][c];
  __builtin_amdgcn_wave_barrier();   // all agg reads precede feats writes below
  union { uint_t u[4]; bf16x8 b; } cv;
  cv.u[0] = pk(av2[0], av2[1]); cv.u[1] = pk(av2[2], av2[3]);
  cv.u[2] = pk(av2[4], av2[5]); cv.u[3] = pk(av2[6], av2[7]);
  bf16x8 afrag = cv.b;
  const ushort_t* wmixl = wmixb + layer * 4096;
  f32x4 o[8];
#pragma unroll
  for (int nt = 0; nt < 8; ++nt) {
    bf16x8 bfm = *(const bf16x8*)&wmixl[(nt * 16 + c) * 32 + quad * 8];
    f32x4 z = {0.0f, 0.0f, 0.0f, 0.0f};
    o[nt] = __builtin_amdgcn_mfma_f32_16x16x32_bf16(afrag, bfm, z, 0, 0, 0);
  }
  // C layout: o[nt][jj] = out[row=k=quad*4+jj][col=nt*16+c]; lq(col)=nt>>1,
  // d = (nt&1)*16 + c. Keep only cols whose lq == L_OF_LM[k].
#pragma unroll
  for (int jj = 0; jj < 4; ++jj) {
    int k = quad * 4 + jj;
    int lq = (k >= 1) + (k >= 4) + (k >= 9);
    float vlo = (lq == 0) ? o[0][jj] : (lq == 1) ? o[2][jj]
              : (lq == 2) ? o[4][jj] : o[6][jj];
    float vhi = (lq == 0) ? o[1][jj] : (lq == 1) ? o[3][jj]
              : (lq == 2) ? o[5][jj] : o[7][jj];
    lbuf[w][c][k] = vlo;                 // feats[d][k] (aliases dead agg data)
    lbuf[w][c + 16][k] = vhi;
  }
  __builtin_amdgcn_wave_barrier();

  // ---- epilogue: poly + skip ----
  int d = lane >> 1;
  int kh = lane & 1;
  int kb = kh * 8;
  float ft[8];
#pragma unroll
  for (int j = 0; j < 8; ++j) ft[j] = lbuf[w][d][kb + j];
  float sv = lbuf[w][d][0];                // k=0 (pre-poly)
  const float* Wp = W_prod + layer * 96;
  float p0 = Wp[d], p1 = Wp[32 + d], p2 = Wp[64 + d];
  float poly = fmaf(fmaf(p2, sv, p1), sv, p0);
#pragma unroll
  for (int j = 0; j < 8; ++j) ft[j] *= poly;
  if (layer == 0 && kh == 0) ft[0] += sc_skip[n * CC + d];
  if (kh == 0) {
    scal_out[n * CC + d] = ft[0];
    lf[w][d][0] = ft[0]; lf[w][d][1] = ft[1]; lf[w][d][2] = ft[2]; lf[w][d][3] = ft[3];
  }
  __builtin_amdgcn_wave_barrier();
  // all-lane readout: part p = lane>>4 sums dd in [p*8, p*8+8), 2-step reduce
  {
    int p = lane >> 4, m = lane & 15;
    float sum = 0.0f;
    if (m < 13) {
      if (m < 10) {
        const float* Wr = W_ro_s + layer * CC * NEL;
#pragma unroll
        for (int q = 0; q < 8; ++q) {
          int dd = p * 8 + q;
          sum = fmaf(lf[w][dd][0], Wr[dd * NEL + m], sum);
        }
      } else {
        int mm = m - 10;
        const float* Wv = W_ro_v + layer * CC;
#pragma unroll
        for (int q = 0; q < 8; ++q) {
          int dd = p * 8 + q;
          sum = fmaf(lf[w][dd][1 + mm], Wv[dd], sum);
        }
      }
    }
    sum += __shfl_down(sum, 32, 64);
    sum += __shfl_down(sum, 16, 64);
    if (lane < 13) pred[n * 13 + lane] += sum;
  }
}

// ---------------- K7: loss accumulation (hierarchical: LDS -> global) --------
__global__ __launch_bounds__(256) void k_loss(const float* __restrict__ pred,
    const float* __restrict__ eps, const int* __restrict__ batch,
    float* __restrict__ lnum, float* __restrict__ lcnt)
{
  __shared__ float psum[GG];
  __shared__ int pcnt[GG];
  int tid = threadIdx.x;
  if (tid < GG) { psum[tid] = 0.0f; pcnt[tid] = 0; }
  __syncthreads();
  int n = blockIdx.x * 256 + tid;
  if (n < NN) {
    int g = batch[n];
    float sum = 0.0f;
#pragma unroll
    for (int j = 0; j < 13; ++j) {
      float dlt = pred[n * 13 + j] - eps[n * 13 + j];
      sum = fmaf(dlt, dlt, sum);
    }
    atomicAdd(&psum[g], sum);   // LDS atomic; batch sorted -> 1-2 distinct g per block
    atomicAdd(&pcnt[g], 1);
  }
  __syncthreads();
  if (tid < GG && pcnt[tid] > 0) {
    atomicAdd(&lnum[tid], psum[tid]);
    atomicAdd(&lcnt[tid], (float)pcnt[tid]);
  }
}

__global__ void k_final(const float* __restrict__ lnum, const float* __restrict__ lcnt,
    float* __restrict__ out)
{
  int g = threadIdx.x;
  if (g < GG) {
    float nn = fmaxf(lcnt[g], 1.0f);
    out[g] = 0.5f * lnum[g] / (nn * 13.0f);
  }
}

extern "C" void kernel_launch(void* const* d_in, const int* in_sizes, int n_in,
                              void* d_out, int out_size, void* d_ws, size_t ws_size,
                              hipStream_t stream) {
  const float* positions  = (const float*)d_in[0];
  const float* node_attrs = (const float*)d_in[1];
  const float* shifts     = (const float*)d_in[2];
  const float* eps        = (const float*)d_in[3];
  const float* alpha_bar  = (const float*)d_in[4];
  const float* W_embed    = (const float*)d_in[5];
  const float* W_r1       = (const float*)d_in[6];
  const float* W_r2       = (const float*)d_in[7];
  const float* W_mix      = (const float*)d_in[8];
  const float* W_sc       = (const float*)d_in[9];
  const float* W_prod     = (const float*)d_in[10];
  const float* W_ro_s     = (const float*)d_in[11];
  const float* W_ro_v     = (const float*)d_in[12];
  const int* edge_index   = (const int*)d_in[13];
  const int* batch        = (const int*)d_in[14];
  const int* tarr         = (const int*)d_in[15];
  float* out = (float*)d_out;

  char* ws = (char*)d_ws;
  size_t off = 0;
  auto alloc = [&](size_t bytes) -> void* {
    void* p = ws + off;
    off = (off + bytes + 255) & ~(size_t)255;
    return p;
  };
  // total ~97 MB (ws_size = 256 MiB)
  float* pos_noisy = (float*)alloc(NN * 3 * 4);
  float* scalA     = (float*)alloc(NN * CC * 4);
  float* scalB     = (float*)alloc(NN * CC * 4);
  float* sc_skip   = (float*)alloc(NN * CC * 4);
  float* pred      = (float*)alloc(NN * 13 * 4);
  ushort_t* YT     = (ushort_t*)alloc((size_t)EE * 16 * 2);       // per-tile [k][e]
  ushort_t* efs    = (ushort_t*)alloc((size_t)EE * 8 * 2);        // sorted, bf16
  int* snds        = (int*)alloc((size_t)EE * 4);                 // sorted sender ids
  ushort_t* rwT    = (ushort_t*)alloc((size_t)EE * 128 * 2);      // rw*ss, per-tile [col][e]
  ushort_t* w2tg   = (ushort_t*)alloc(2 * HIDD * 128 * 2);        // W2^T bf16, both layers
  ushort_t* wmixb  = (ushort_t*)alloc(2 * 128 * CC * 2);          // Wmix packed, both layers
  int* deg         = (int*)alloc(NN * 4);
  int* offs        = (int*)alloc((NN + 1) * 4);
  int* cursor      = (int*)alloc(NN * 4);
  float* lnum      = (float*)alloc(GG * 4);
  float* lcnt      = (float*)alloc(GG * 4);
  (void)ws_size; (void)in_sizes; (void)n_in; (void)out_size;

  const int NB_N = (NN + 255) / 256;   // 79
  const int NB_E = EE / 256;           // 1250

  k_prep<<<NB_N + 96, 256, 0, stream>>>(positions, node_attrs, eps, alpha_bar,
                                        W_embed, W_sc, W_r2, W_mix, batch, tarr,
                                        pos_noisy, scalA, sc_skip, pred, deg,
                                        w2tg, wmixb);
  k_edge_deg<<<NB_E, 256, 0, stream>>>(edge_index, deg);
  k_scan<<<1, 1024, 0, stream>>>(deg, offs, cursor, lnum, lcnt);
  k_edge2<<<NB_E, 256, 0, stream>>>(pos_noisy, shifts, edge_index, cursor, YT, efs, snds);

  for (int layer = 0; layer < 2; ++layer) {
    const float* sin_p = (layer == 0) ? scalA : scalB;
    float* sout_p      = (layer == 0) ? scalB : scalA;
    k_rw_mfma<<<NB_E, 256, 0, stream>>>(efs, W_r1, w2tg, snds, sin_p, rwT, layer);
    k_layer<<<NN / 4, 256, 0, stream>>>(YT, rwT, sout_p, offs,
                                        wmixb, W_prod, W_ro_s, W_ro_v,
                                        sc_skip, pred, layer);
  }

  k_loss<<<NB_N, 256, 0, stream>>>(pred, eps, batch, lnum, lcnt);
  k_final<<<1, 64, 0, stream>>>(lnum, lcnt, out);
}

// Round 10
// 296.851 us; speedup vs baseline: 1.0484x; 1.0484x over previous
//
#include <hip/hip_runtime.h>

typedef unsigned short ushort_t;
typedef unsigned int uint_t;

#define NN 20000
#define EE 320000
#define CC 32
#define NEL 10
#define GG 64
#define TTT 1000
#define NBB 8
#define HIDD 64
#define EPB 256         // edges per block in k_rw_mfma (EE = 1250*256 exactly)
#define NTILE (EE / 16) // 20000 16-slot tiles

typedef __attribute__((ext_vector_type(8))) short bf16x8;
typedef __attribute__((ext_vector_type(4))) float f32x4;

__device__ __forceinline__ float bits2f(uint_t b) { union { uint_t u; float f; } v; v.u = b; return v.f; }
__device__ __forceinline__ ushort_t f2b(float f) {
  union { float f; uint_t u; } v; v.f = f;
  uint_t r = (v.u + 0x7fffu + ((v.u >> 16) & 1u)) >> 16;
  return (ushort_t)r;
}
// single-instruction packed f32->bf16 (RNE, same as f2b) [gfx950 v_cvt_pk_bf16_f32]
__device__ __forceinline__ uint_t pk(float a, float b) {
  uint_t r;
  asm("v_cvt_pk_bf16_f32 %0, %1, %2" : "=v"(r) : "v"(a), "v"(b));
  return r;
}
__device__ __forceinline__ float lo16(uint_t u) { return bits2f(u << 16); }
__device__ __forceinline__ float hi16(uint_t u) { return bits2f(u & 0xffff0000u); }
// fast reciprocal (v_rcp_f32, ~2^-22 rel err) -- outputs here are bf16 (2^-8)
__device__ __forceinline__ float frcp(float x) { return __builtin_amdgcn_rcpf(x); }

// ---------------- K1: node prep (zeroes deg) + weight packing (merged) -------
// blocks [0,79): node prep; blocks [79,179): pack W2^T / Wmix / W1 to bf16
__global__ __launch_bounds__(256) void k_prep(
    const float* __restrict__ positions, const float* __restrict__ node_attrs,
    const float* __restrict__ eps, const float* __restrict__ alpha_bar,
    const float* __restrict__ W_embed, const float* __restrict__ W_sc,
    const float* __restrict__ W_r1, const float* __restrict__ W_r2,
    const float* __restrict__ W_mix,
    const int* __restrict__ batch, const int* __restrict__ tarr,
    float* __restrict__ pos_noisy, float* __restrict__ scalA,
    float* __restrict__ sc_skip, float* __restrict__ pred, int* __restrict__ deg,
    ushort_t* __restrict__ w2tg, ushort_t* __restrict__ wmixb,
    ushort_t* __restrict__ w1pg)
{
  if (blockIdx.x >= 79) {   // ---- weight-pack role ----
    int idx = (blockIdx.x - 79) * 256 + threadIdx.x;   // 100*256 = 25600
    if (idx < 16384) {
      int l = idx >> 13, r = idx & 8191;
      int n = r >> 6, k = r & 63;
      w2tg[idx] = f2b(W_r2[l * 8192 + k * 128 + n]);
    } else if (idx < 24576) {
      int r = idx - 16384;
      int l = r >> 12, r2 = r & 4095;
      int col = r2 >> 5, ch = r2 & 31;
      int lq = col >> 5, d = col & 31;
      wmixb[r] = f2b(W_mix[l * 4096 + lq * 1024 + ch * 32 + d]);
    } else {
      // w1pg[l][h*8+b] = bf16(W_r1[l][b*64+h])  (B-frag friendly [col][k])
      int r = idx - 24576;   // 1024 entries
      int l = r >> 9, r2 = r & 511;
      int h = r2 >> 3, b = r2 & 7;
      w1pg[r] = f2b(W_r1[l * 512 + b * 64 + h]);
    }
    return;
  }
  int n = blockIdx.x * 256 + threadIdx.x;
  if (n >= NN) return;
  deg[n] = 0;
  int g = batch[n];
  int tn = tarr[g];
  float ab = alpha_bar[tn];
  float sa = sqrtf(ab), sb = sqrtf(fmaxf(1.0f - ab, 0.0f));
#pragma unroll
  for (int j = 0; j < 3; ++j)
    pos_noisy[n * 3 + j] = sa * positions[n * 3 + j] + sb * eps[n * 13 + 10 + j];
  float an[10];
#pragma unroll
  for (int j = 0; j < 10; ++j)
    an[j] = sa * 0.25f * node_attrs[n * 10 + j] + sb * eps[n * 13 + j];
  float tf = (float)tn * (1.0f / (float)TTT);
  for (int d = 0; d < CC; ++d) {
    float h = tf * W_embed[10 * CC + d];
    float sk = 0.0f;
#pragma unroll
    for (int j = 0; j < 10; ++j) {
      h = fmaf(an[j], W_embed[j * CC + d], h);
      sk = fmaf(an[j], W_sc[j * CC + d], sk);
    }
    scalA[n * CC + d] = h;
    sc_skip[n * CC + d] = sk;
  }
#pragma unroll
  for (int j = 0; j < 13; ++j) pred[n * 13 + j] = 0.0f;
}

// ---------------- K2a: receiver histogram ----------------
__global__ __launch_bounds__(256) void k_edge_deg(const int* __restrict__ ei,
    int* __restrict__ deg)
{
  int e = blockIdx.x * 256 + threadIdx.x;  // EE = 1250*256 exactly
  atomicAdd(&deg[ei[EE + e]], 1);
}

// ---------------- K3: exclusive scan deg -> offs, cursor; zero loss accum ----
__global__ __launch_bounds__(1024) void k_scan(const int* __restrict__ deg,
    int* __restrict__ offs, int* __restrict__ cursor,
    float* __restrict__ lnum, float* __restrict__ lcnt)
{
  __shared__ int wsums[16];
  __shared__ int woffs[16];
  int tid = threadIdx.x, lane = tid & 63, wv = tid >> 6;
  if (tid < GG) { lnum[tid] = 0.0f; lcnt[tid] = 0.0f; }
  int base = tid * 20;
  int loc[20];
  int s = 0;
#pragma unroll
  for (int j = 0; j < 20; ++j) {
    int idx = base + j;
    int v = (idx < NN) ? deg[idx] : 0;
    loc[j] = s; s += v;
  }
  int inc = s;
  for (int o = 1; o < 64; o <<= 1) {
    int v = __shfl_up(inc, o, 64);
    if (lane >= o) inc += v;
  }
  if (lane == 63) wsums[wv] = inc;
  __syncthreads();
  if (wv == 0 && lane < 16) {
    int v = wsums[lane];
    int i2 = v;
    for (int o = 1; o < 16; o <<= 1) {
      int vv = __shfl_up(i2, o, 16);
      if (lane >= o) i2 += vv;
    }
    woffs[lane] = i2 - v;
  }
  __syncthreads();
  int texcl = woffs[wv] + (inc - s);
#pragma unroll
  for (int j = 0; j < 20; ++j) {
    int idx = base + j;
    if (idx < NN) { int v = texcl + loc[j]; offs[idx] = v; cursor[idx] = v; }
  }
  if (tid == 1023) offs[NN] = EE;
}

// ---------------- K4: edge geometry, written into receiver-sorted slots ------
__global__ __launch_bounds__(256) void k_edge2(
    const float* __restrict__ pos_noisy, const float* __restrict__ shifts,
    const int* __restrict__ ei, int* __restrict__ cursor,
    ushort_t* __restrict__ Ys, ushort_t* __restrict__ efs, int* __restrict__ snds)
{
  int e = blockIdx.x * 256 + threadIdx.x;  // EE exact
  int snd = ei[e], rcv = ei[EE + e];
  float vx = pos_noisy[rcv * 3 + 0] - pos_noisy[snd * 3 + 0] + shifts[e * 3 + 0];
  float vy = pos_noisy[rcv * 3 + 1] - pos_noisy[snd * 3 + 1] + shifts[e * 3 + 1];
  float vz = pos_noisy[rcv * 3 + 2] - pos_noisy[snd * 3 + 2] + shifts[e * 3 + 2];
  float r2 = vx * vx + vy * vy + vz * vz + 1e-12f;
  float r = sqrtf(r2);
  float inv = frcp(r);            // feeds bf16 outputs only
  float x = vx * inv, y = vy * inv, z = vz * inv;

  const float s3 = 1.7320508075688772f, s15 = 3.872983346207417f, s5 = 2.23606797749979f;
  const float s105 = 10.246950765959598f, s7 = 2.6457513110645907f;
  const float s35_8 = 2.091650066335189f, s21_8 = 1.6201851746019651f;
  float yv[16];
  yv[0] = 1.0f;
  yv[1] = s3 * x; yv[2] = s3 * y; yv[3] = s3 * z;
  yv[4] = s15 * x * y;
  yv[5] = s15 * y * z;
  yv[6] = 0.5f * s5 * (3.0f * z * z - 1.0f);
  yv[7] = s15 * x * z;
  yv[8] = 0.5f * s15 * (x * x - y * y);
  yv[9] = s35_8 * y * (3.0f * x * x - y * y);
  yv[10] = s105 * x * y * z;
  yv[11] = s21_8 * y * (5.0f * z * z - 1.0f);
  yv[12] = 0.5f * s7 * (5.0f * z * z * z - 3.0f * z);
  yv[13] = s21_8 * x * (5.0f * z * z - 1.0f);
  yv[14] = 0.5f * s105 * z * (x * x - y * y);
  yv[15] = s35_8 * x * (x * x - 3.0f * y * y);

  // radial embed: sqrt(2/5) * sin(n*pi*rc/5)/rc * poly_cutoff(r/5)
  float rc = fmaxf(r, 1e-9f);
  float pref = 0.6324555320336759f * frcp(rc);   // bf16 output -> fast rcp ok
  float th = 0.6283185307179586f * rc;
  float s1 = __sinf(th), c1 = __cosf(th);
  float xr = r * 0.2f;
  float fcut = 0.0f;
  if (xr < 1.0f) {
    float x2 = xr * xr, x3 = x2 * xr;
    float x6 = x3 * x3, x7 = x6 * xr, x8 = x7 * xr;
    fcut = 1.0f - 28.0f * x6 + 48.0f * x7 - 21.0f * x8;
  }
  float efv[8];
  float sp = 0.0f, scur = s1, c2 = 2.0f * c1;
#pragma unroll
  for (int b = 0; b < 8; ++b) {
    efv[b] = pref * scur * fcut;
    float nx = c2 * scur - sp;   // sin((n+1)th) = 2cos(th)sin(n th) - sin((n-1)th)
    sp = scur; scur = nx;
  }

  int slot = atomicAdd(&cursor[rcv], 1);
  snds[slot] = snd;
  uint4* Y4 = (uint4*)Ys;
  Y4[(size_t)slot * 2 + 0] = make_uint4(pk(yv[0], yv[1]), pk(yv[2], yv[3]),
                                        pk(yv[4], yv[5]), pk(yv[6], yv[7]));
  Y4[(size_t)slot * 2 + 1] = make_uint4(pk(yv[8], yv[9]), pk(yv[10], yv[11]),
                                        pk(yv[12], yv[13]), pk(yv[14], yv[15]));
  ((uint4*)efs)[slot] = make_uint4(pk(efv[0], efv[1]), pk(efv[2], efv[3]),
                                   pk(efv[4], efv[5]), pk(efv[6], efv[7]));
}

// ---------------- K4b: transpose Y into per-tile [k][e] layout ----------------
__global__ __launch_bounds__(256) void k_ytr(const ushort_t* __restrict__ Ys,
    ushort_t* __restrict__ YT)
{
  int idx = blockIdx.x * 256 + threadIdx.x;  // NTILE*16 = 320000 = 1250*256 exact
  int tile = idx >> 4, k = idx & 15;
  ushort_t v[16];
#pragma unroll
  for (int el = 0; el < 16; ++el)
    v[el] = Ys[(size_t)(tile * 16 + el) * 16 + k];
  uint_t u[8];
#pragma unroll
  for (int p = 0; p < 8; ++p) u[p] = (uint_t)v[2 * p] | ((uint_t)v[2 * p + 1] << 16);
  uint4* o = (uint4*)(YT + (size_t)tile * 256 + (size_t)k * 16);
  o[0] = make_uint4(u[0], u[1], u[2], u[3]);
  o[1] = make_uint4(u[4], u[5], u[6], u[7]);
}

// ---------------- K5: edge radial MLP via MFMA (GEMM1 now MFMA too) ----------
// GEMM1: [256 x 8]@[8 x 64] via 16x16x32 MFMA, K=8 zero-padded (quad 0 only
// holds real A/B data); silu applied on C; h1 -> LDS. GEMM2 unchanged.
__global__ __launch_bounds__(256) void k_rw_mfma(
    const ushort_t* __restrict__ efs, const ushort_t* __restrict__ w1pg,
    const ushort_t* __restrict__ w2tg, const int* __restrict__ snds,
    const float* __restrict__ scal_in, ushort_t* __restrict__ rwT, int layer)
{
  __shared__ __align__(16) ushort_t h1[EPB][72];    // silu(ef@W1) bf16, padded
  int tid = threadIdx.x;
  int w = tid >> 6, lane = tid & 63;
  int c = lane & 15, quad = lane >> 4;
  const ushort_t* w1l = w1pg + layer * (HIDD * NBB);
  const ushort_t* w2l = w2tg + layer * (HIDD * 128);
  const bf16x8 bz = (bf16x8){0, 0, 0, 0, 0, 0, 0, 0};
  int mb0 = w * 64;   // this wave covers 64 edges = 4 m-tiles

  // ---- stage 1: h1 = silu(ef @ W1) via MFMA ----
  {
    bf16x8 bW[4];   // B-frag: w1l[col=h][k=b], quad 0 real, quads 1-3 zero
#pragma unroll
    for (int nt = 0; nt < 4; ++nt)
      bW[nt] = (quad == 0) ? *(const bf16x8*)&w1l[(nt * 16 + c) * NBB] : bz;
#pragma unroll
    for (int mt = 0; mt < 4; ++mt) {
      int mbase = mb0 + mt * 16;
      bf16x8 aE = bz;   // A-frag: edge c's 8 ef values at k=0..7 (quad 0)
      if (quad == 0)
        aE = ((const bf16x8*)efs)[(size_t)blockIdx.x * EPB + mbase + c];
#pragma unroll
      for (int nt = 0; nt < 4; ++nt) {
        f32x4 acc = {0.0f, 0.0f, 0.0f, 0.0f};
        acc = __builtin_amdgcn_mfma_f32_16x16x32_bf16(aE, bW[nt], acc, 0, 0, 0);
        // C layout: acc[j] = h1_pre[edge = mbase+quad*4+j][h = nt*16+c]
#pragma unroll
        for (int j = 0; j < 4; ++j) {
          float t = acc[j];
          float s = t * frcp(1.0f + __expf(-t));   // silu, fast rcp (bf16 out)
          h1[mbase + quad * 4 + j][nt * 16 + c] = (ushort_t)pk(s, s);
        }
      }
    }
  }
  __builtin_amdgcn_wave_barrier();   // h1 rows are wave-private (64 rows per wave)

  // all 16 B-fragments (8 n-tiles x 2 k-tiles) from global bf16 (L1-hot, hoisted)
  bf16x8 bfr[16];
#pragma unroll
  for (int nt = 0; nt < 8; ++nt)
#pragma unroll
    for (int kt = 0; kt < 2; ++kt)
      bfr[nt * 2 + kt] = *(const bf16x8*)&w2l[(nt * 16 + c) * 64 + kt * 32 + quad * 8];
#pragma unroll
  for (int mt = 0; mt < 4; ++mt) {
    int mbase = mb0 + mt * 16;
    bf16x8 a0 = *(const bf16x8*)&h1[mbase + c][quad * 8];
    bf16x8 a1 = *(const bf16x8*)&h1[mbase + c][32 + quad * 8];
    size_t erow = (size_t)blockIdx.x * EPB + mbase + quad * 4;
    int4 sn = *(const int4*)&snds[erow];     // 4 consecutive edges' senders
    const float* sb0 = scal_in + (size_t)sn.x * CC;
    const float* sb1 = scal_in + (size_t)sn.y * CC;
    const float* sb2 = scal_in + (size_t)sn.z * CC;
    const float* sb3 = scal_in + (size_t)sn.w * CC;
    int tile = blockIdx.x * 16 + w * 4 + mt;  // global 16-slot tile index
#pragma unroll
    for (int nt = 0; nt < 8; ++nt) {
      f32x4 acc = {0.0f, 0.0f, 0.0f, 0.0f};
      acc = __builtin_amdgcn_mfma_f32_16x16x32_bf16(a0, bfr[nt * 2 + 0], acc, 0, 0, 0);
      acc = __builtin_amdgcn_mfma_f32_16x16x32_bf16(a1, bfr[nt * 2 + 1], acc, 0, 0, 0);
      int col = nt * 16 + c;
      int cc = col >> 2;                     // channel = col/4 (col = 4c+l)
      // C layout: acc[j] is edge (quad*4+j) of this tile, fixed col.
      uint2 st;
      st.x = pk(acc[0] * sb0[cc], acc[1] * sb1[cc]);
      st.y = pk(acc[2] * sb2[cc], acc[3] * sb3[cc]);
      *(uint2*)(rwT + (size_t)tile * 2048 + (size_t)col * 16 + quad * 4) = st;
    }
  }
}

// ---------------- K6: MFMA segment-aggregate + MFMA mix + poly + readout -----
// LDS: single aliased buffer lbuf holds agg[ch][k] then feats[d][k] (the agg
// data is fully consumed by the mix A-frag reads before feats is written;
// per-wave LDS is in-order and the wave executes in lockstep -> no race).
__global__ __launch_bounds__(256) void k_layer(
    const ushort_t* __restrict__ YT, const ushort_t* __restrict__ rwT,
    float* __restrict__ scal_out,
    const int* __restrict__ offs,
    const ushort_t* __restrict__ wmixb, const float* __restrict__ W_prod,
    const float* __restrict__ W_ro_s, const float* __restrict__ W_ro_v,
    const float* __restrict__ sc_skip, float* __restrict__ pred, int layer)
{
  __shared__ float lbuf[4][CC][17];    // 8.7 KB (aliased agg/feats), pad 17
  __shared__ float lf[4][CC][4];       // 2 KB
  int w = threadIdx.x >> 6, lane = threadIdx.x & 63;
  int n = blockIdx.x * 4 + w;        // NN = 5000*4 exactly
  int c = lane & 15, quad = lane >> 4;
  int i0 = offs[n], i1 = offs[n + 1];
  int t0 = i0 >> 4, t1 = (i1 + 15) >> 4;   // tiles overlapping this node
  int tsel = quad >> 1, half8 = quad & 1;
  f32x4 acc[8];
#pragma unroll
  for (int mt = 0; mt < 8; ++mt) acc[mt] = (f32x4){0.0f, 0.0f, 0.0f, 0.0f};

  for (int t = t0; t < t1; t += 2) {       // K = 32 edges per step (2 tiles)
    int ta = t + tsel;                      // quad pair 0/1 -> tile t, 2/3 -> t+1
    bf16x8 a[8];
    bf16x8 b;
    int sbase = ta * 16 + half8 * 8;
    // this quad-half contributes iff its 8-slot range intersects the segment
    bool av = (sbase < i1) && (sbase + 8 > i0) && (ta < t1);
    if (av) {
      const bf16x8* ap = (const bf16x8*)rwT + (size_t)ta * 256 + c * 2 + half8;
#pragma unroll
      for (int mt = 0; mt < 8; ++mt) a[mt] = ap[mt * 32];
      b = ((const bf16x8*)YT)[(size_t)ta * 32 + c * 2 + half8];
      if (sbase < i0 || sbase + 8 > i1) {
#pragma unroll
        for (int j = 0; j < 8; ++j) {
          int s = sbase + j;
          if (s < i0 || s >= i1) b[j] = 0;   // zero Y outside segment -> 0 contrib
        }
      }
    } else {
#pragma unroll
      for (int mt = 0; mt < 8; ++mt) a[mt] = (bf16x8){0, 0, 0, 0, 0, 0, 0, 0};
      b = (bf16x8){0, 0, 0, 0, 0, 0, 0, 0};
    }
#pragma unroll
    for (int mt = 0; mt < 8; ++mt)
      acc[mt] = __builtin_amdgcn_mfma_f32_16x16x32_bf16(a[mt], b, acc[mt], 0, 0, 0);
  }

  // C layout: acc[mt][j] = agg_full[row = mt*16 + quad*4 + j][k = c]
  //   -> channel = mt*4 + quad, kk = j; select j = L_OF_LM[c]
  int lc = (c >= 1) + (c >= 4) + (c >= 9);
  const float inva = 1.0f / 16.0f;
#pragma unroll
  for (int mt = 0; mt < 8; ++mt) {
    float v = (lc == 0) ? acc[mt][0] : (lc == 1) ? acc[mt][1]
            : (lc == 2) ? acc[mt][2] : acc[mt][3];
    lbuf[w][mt * 4 + quad][c] = v * inva;    // agg[ch][k]
  }
  __builtin_amdgcn_wave_barrier();

  // ---- mix via MFMA: out[k][lq*32+d] = sum_ch agg[ch][k] * Wm[lq][ch][d] ----
  float av2[8];
#pragma unroll
  for (int j = 0; j < 8; ++j) av2[j] = lbuf[w][quad * 8 + j][c];
  __builtin_amdgcn_wave_barrier();   // all agg reads precede feats writes below
  union { uint_t u[4]; bf16x8 b; } cv;
  cv.u[0] = pk(av2[0], av2[1]); cv.u[1] = pk(av2[2], av2[3]);
  cv.u[2] = pk(av2[4], av2[5]); cv.u[3] = pk(av2[6], av2[7]);
  bf16x8 afrag = cv.b;
  const ushort_t* wmixl = wmixb + layer * 4096;
  f32x4 o[8];
#pragma unroll
  for (int nt = 0; nt < 8; ++nt) {
    bf16x8 bfm = *(const bf16x8*)&wmixl[(nt * 16 + c) * 32 + quad * 8];
    f32x4 z = {0.0f, 0.0f, 0.0f, 0.0f};
    o[nt] = __builtin_amdgcn_mfma_f32_16x16x32_bf16(afrag, bfm, z, 0, 0, 0);
  }
  // C layout: o[nt][jj] = out[row=k=quad*4+jj][col=nt*16+c]; lq(col)=nt>>1,
  // d = (nt&1)*16 + c. Keep only cols whose lq == L_OF_LM[k].
#pragma unroll
  for (int jj = 0; jj < 4; ++jj) {
    int k = quad * 4 + jj;
    int lq = (k >= 1) + (k >= 4) + (k >= 9);
    float vlo = (lq == 0) ? o[0][jj] : (lq == 1) ? o[2][jj]
              : (lq == 2) ? o[4][jj] : o[6][jj];
    float vhi = (lq == 0) ? o[1][jj] : (lq == 1) ? o[3][jj]
              : (lq == 2) ? o[5][jj] : o[7][jj];
    lbuf[w][c][k] = vlo;                 // feats[d][k] (aliases dead agg data)
    lbuf[w][c + 16][k] = vhi;
  }
  __builtin_amdgcn_wave_barrier();

  // ---- epilogue: poly + skip ----
  int d = lane >> 1;
  int kh = lane & 1;
  int kb = kh * 8;
  float ft[8];
#pragma unroll
  for (int j = 0; j < 8; ++j) ft[j] = lbuf[w][d][kb + j];
  float sv = lbuf[w][d][0];                // k=0 (pre-poly)
  const float* Wp = W_prod + layer * 96;
  float p0 = Wp[d], p1 = Wp[32 + d], p2 = Wp[64 + d];
  float poly = fmaf(fmaf(p2, sv, p1), sv, p0);
#pragma unroll
  for (int j = 0; j < 8; ++j) ft[j] *= poly;
  if (layer == 0 && kh == 0) ft[0] += sc_skip[n * CC + d];
  if (kh == 0) {
    scal_out[n * CC + d] = ft[0];
    lf[w][d][0] = ft[0]; lf[w][d][1] = ft[1]; lf[w][d][2] = ft[2]; lf[w][d][3] = ft[3];
  }
  __builtin_amdgcn_wave_barrier();
  // all-lane readout: part p = lane>>4 sums dd in [p*8, p*8+8), 2-step reduce
  {
    int p = lane >> 4, m = lane & 15;
    float sum = 0.0f;
    if (m < 13) {
      if (m < 10) {
        const float* Wr = W_ro_s + layer * CC * NEL;
#pragma unroll
        for (int q = 0; q < 8; ++q) {
          int dd = p * 8 + q;
          sum = fmaf(lf[w][dd][0], Wr[dd * NEL + m], sum);
        }
      } else {
        int mm = m - 10;
        const float* Wv = W_ro_v + layer * CC;
#pragma unroll
        for (int q = 0; q < 8; ++q) {
          int dd = p * 8 + q;
          sum = fmaf(lf[w][dd][1 + mm], Wv[dd], sum);
        }
      }
    }
    sum += __shfl_down(sum, 32, 64);
    sum += __shfl_down(sum, 16, 64);
    if (lane < 13) pred[n * 13 + lane] += sum;
  }
}

// ---------------- K7: loss accumulation (hierarchical: LDS -> global) --------
__global__ __launch_bounds__(256) void k_loss(const float* __restrict__ pred,
    const float* __restrict__ eps, const int* __restrict__ batch,
    float* __restrict__ lnum, float* __restrict__ lcnt)
{
  __shared__ float psum[GG];
  __shared__ int pcnt[GG];
  int tid = threadIdx.x;
  if (tid < GG) { psum[tid] = 0.0f; pcnt[tid] = 0; }
  __syncthreads();
  int n = blockIdx.x * 256 + tid;
  if (n < NN) {
    int g = batch[n];
    float sum = 0.0f;
#pragma unroll
    for (int j = 0; j < 13; ++j) {
      float dlt = pred[n * 13 + j] - eps[n * 13 + j];
      sum = fmaf(dlt, dlt, sum);
    }
    atomicAdd(&psum[g], sum);   // LDS atomic; batch sorted -> 1-2 distinct g per block
    atomicAdd(&pcnt[g], 1);
  }
  __syncthreads();
  if (tid < GG && pcnt[tid] > 0) {
    atomicAdd(&lnum[tid], psum[tid]);
    atomicAdd(&lcnt[tid], (float)pcnt[tid]);
  }
}

__global__ void k_final(const float* __restrict__ lnum, const float* __restrict__ lcnt,
    float* __restrict__ out)
{
  int g = threadIdx.x;
  if (g < GG) {
    float nn = fmaxf(lcnt[g], 1.0f);
    out[g] = 0.5f * lnum[g] / (nn * 13.0f);
  }
}

extern "C" void kernel_launch(void* const* d_in, const int* in_sizes, int n_in,
                              void* d_out, int out_size, void* d_ws, size_t ws_size,
                              hipStream_t stream) {
  const float* positions  = (const float*)d_in[0];
  const float* node_attrs = (const float*)d_in[1];
  const float* shifts     = (const float*)d_in[2];
  const float* eps        = (const float*)d_in[3];
  const float* alpha_bar  = (const float*)d_in[4];
  const float* W_embed    = (const float*)d_in[5];
  const float* W_r1       = (const float*)d_in[6];
  const float* W_r2       = (const float*)d_in[7];
  const float* W_mix      = (const float*)d_in[8];
  const float* W_sc       = (const float*)d_in[9];
  const float* W_prod     = (const float*)d_in[10];
  const float* W_ro_s     = (const float*)d_in[11];
  const float* W_ro_v     = (const float*)d_in[12];
  const int* edge_index   = (const int*)d_in[13];
  const int* batch        = (const int*)d_in[14];
  const int* tarr         = (const int*)d_in[15];
  float* out = (float*)d_out;

  char* ws = (char*)d_ws;
  size_t off = 0;
  auto alloc = [&](size_t bytes) -> void* {
    void* p = ws + off;
    off = (off + bytes + 255) & ~(size_t)255;
    return p;
  };
  // total ~107 MB (ws_size = 256 MiB)
  float* pos_noisy = (float*)alloc(NN * 3 * 4);
  float* scalA     = (float*)alloc(NN * CC * 4);
  float* scalB     = (float*)alloc(NN * CC * 4);
  float* sc_skip   = (float*)alloc(NN * CC * 4);
  float* pred      = (float*)alloc(NN * 13 * 4);
  ushort_t* Ys     = (ushort_t*)alloc((size_t)EE * 16 * 2);       // sorted, bf16 [slot][k]
  ushort_t* YT     = (ushort_t*)alloc((size_t)EE * 16 * 2);       // per-tile [k][e]
  ushort_t* efs    = (ushort_t*)alloc((size_t)EE * 8 * 2);        // sorted, bf16
  int* snds        = (int*)alloc((size_t)EE * 4);                 // sorted sender ids
  ushort_t* rwT    = (ushort_t*)alloc((size_t)EE * 128 * 2);      // rw*ss, per-tile [col][e]
  ushort_t* w2tg   = (ushort_t*)alloc(2 * HIDD * 128 * 2);        // W2^T bf16, both layers
  ushort_t* wmixb  = (ushort_t*)alloc(2 * 128 * CC * 2);          // Wmix packed, both layers
  ushort_t* w1pg   = (ushort_t*)alloc(2 * HIDD * NBB * 2);        // W1 packed [h][b], both layers
  int* deg         = (int*)alloc(NN * 4);
  int* offs        = (int*)alloc((NN + 1) * 4);
  int* cursor      = (int*)alloc(NN * 4);
  float* lnum      = (float*)alloc(GG * 4);
  float* lcnt      = (float*)alloc(GG * 4);
  (void)ws_size; (void)in_sizes; (void)n_in; (void)out_size;

  const int NB_N = (NN + 255) / 256;   // 79
  const int NB_E = EE / 256;           // 1250

  k_prep<<<NB_N + 100, 256, 0, stream>>>(positions, node_attrs, eps, alpha_bar,
                                         W_embed, W_sc, W_r1, W_r2, W_mix, batch,
                                         tarr, pos_noisy, scalA, sc_skip, pred,
                                         deg, w2tg, wmixb, w1pg);
  k_edge_deg<<<NB_E, 256, 0, stream>>>(edge_index, deg);
  k_scan<<<1, 1024, 0, stream>>>(deg, offs, cursor, lnum, lcnt);
  k_edge2<<<NB_E, 256, 0, stream>>>(pos_noisy, shifts, edge_index, cursor, Ys, efs, snds);
  k_ytr<<<NB_E, 256, 0, stream>>>(Ys, YT);   // NTILE*16/256 = 1250 blocks exact

  for (int layer = 0; layer < 2; ++layer) {
    const float* sin_p = (layer == 0) ? scalA : scalB;
    float* sout_p      = (layer == 0) ? scalB : scalA;
    k_rw_mfma<<<NB_E, 256, 0, stream>>>(efs, w1pg, w2tg, snds, sin_p, rwT, layer);
    k_layer<<<NN / 4, 256, 0, stream>>>(YT, rwT, sout_p, offs,
                                        wmixb, W_prod, W_ro_s, W_ro_v,
                                        sc_skip, pred, layer);
  }

  k_loss<<<NB_N, 256, 0, stream>>>(pred, eps, batch, lnum, lcnt);
  k_final<<<1, 64, 0, stream>>>(lnum, lcnt, out);
}

// Round 11
// 293.767 us; speedup vs baseline: 1.0594x; 1.0105x over previous
//
#include <hip/hip_runtime.h>

typedef unsigned short ushort_t;
typedef unsigned int uint_t;

#define NN 20000
#define EE 320000
#define CC 32
#define NEL 10
#define GG 64
#define TTT 1000
#define NBB 8
#define HIDD 64
#define EPB 256         // edges per block in k_rw_mfma (EE = 1250*256 exactly)
#define NTILE (EE / 16) // 20000 16-slot tiles

typedef __attribute__((ext_vector_type(8))) short bf16x8;
typedef __attribute__((ext_vector_type(4))) float f32x4;

__device__ __forceinline__ float bits2f(uint_t b) { union { uint_t u; float f; } v; v.u = b; return v.f; }
__device__ __forceinline__ ushort_t f2b(float f) {
  union { float f; uint_t u; } v; v.f = f;
  uint_t r = (v.u + 0x7fffu + ((v.u >> 16) & 1u)) >> 16;
  return (ushort_t)r;
}
// single-instruction packed f32->bf16 (RNE, same as f2b) [gfx950 v_cvt_pk_bf16_f32]
__device__ __forceinline__ uint_t pk(float a, float b) {
  uint_t r;
  asm("v_cvt_pk_bf16_f32 %0, %1, %2" : "=v"(r) : "v"(a), "v"(b));
  return r;
}
__device__ __forceinline__ float lo16(uint_t u) { return bits2f(u << 16); }
__device__ __forceinline__ float hi16(uint_t u) { return bits2f(u & 0xffff0000u); }
// fast reciprocal (v_rcp_f32, ~2^-22 rel err) -- outputs here are bf16 (2^-8)
__device__ __forceinline__ float frcp(float x) { return __builtin_amdgcn_rcpf(x); }

// ---------------- K1: node prep (zeroes deg) + weight packing (merged) -------
// blocks [0,79): node prep; blocks [79,175): pack W2^T / Wmix to bf16 global
__global__ __launch_bounds__(256) void k_prep(
    const float* __restrict__ positions, const float* __restrict__ node_attrs,
    const float* __restrict__ eps, const float* __restrict__ alpha_bar,
    const float* __restrict__ W_embed, const float* __restrict__ W_sc,
    const float* __restrict__ W_r2, const float* __restrict__ W_mix,
    const int* __restrict__ batch, const int* __restrict__ tarr,
    float* __restrict__ pos_noisy, float* __restrict__ scalA,
    float* __restrict__ sc_skip, float* __restrict__ pred, int* __restrict__ deg,
    ushort_t* __restrict__ w2tg, ushort_t* __restrict__ wmixb)
{
  if (blockIdx.x >= 79) {   // ---- weight-pack role ----
    int idx = (blockIdx.x - 79) * 256 + threadIdx.x;   // 96*256 = 24576
    if (idx < 16384) {
      int l = idx >> 13, r = idx & 8191;
      int n = r >> 6, k = r & 63;
      w2tg[idx] = f2b(W_r2[l * 8192 + k * 128 + n]);
    } else {
      int r = idx - 16384;
      int l = r >> 12, r2 = r & 4095;
      int col = r2 >> 5, ch = r2 & 31;
      int lq = col >> 5, d = col & 31;
      wmixb[r] = f2b(W_mix[l * 4096 + lq * 1024 + ch * 32 + d]);
    }
    return;
  }
  int n = blockIdx.x * 256 + threadIdx.x;
  if (n >= NN) return;
  deg[n] = 0;
  int g = batch[n];
  int tn = tarr[g];
  float ab = alpha_bar[tn];
  float sa = sqrtf(ab), sb = sqrtf(fmaxf(1.0f - ab, 0.0f));
#pragma unroll
  for (int j = 0; j < 3; ++j)
    pos_noisy[n * 3 + j] = sa * positions[n * 3 + j] + sb * eps[n * 13 + 10 + j];
  float an[10];
#pragma unroll
  for (int j = 0; j < 10; ++j)
    an[j] = sa * 0.25f * node_attrs[n * 10 + j] + sb * eps[n * 13 + j];
  float tf = (float)tn * (1.0f / (float)TTT);
  for (int d = 0; d < CC; ++d) {
    float h = tf * W_embed[10 * CC + d];
    float sk = 0.0f;
#pragma unroll
    for (int j = 0; j < 10; ++j) {
      h = fmaf(an[j], W_embed[j * CC + d], h);
      sk = fmaf(an[j], W_sc[j * CC + d], sk);
    }
    scalA[n * CC + d] = h;
    sc_skip[n * CC + d] = sk;
  }
#pragma unroll
  for (int j = 0; j < 13; ++j) pred[n * 13 + j] = 0.0f;
}

// ---------------- K2a: receiver histogram ----------------
__global__ __launch_bounds__(256) void k_edge_deg(const int* __restrict__ ei,
    int* __restrict__ deg)
{
  int e = blockIdx.x * 256 + threadIdx.x;  // EE = 1250*256 exactly
  atomicAdd(&deg[ei[EE + e]], 1);
}

// ---------------- K3: exclusive scan deg -> offs, cursor; zero loss accum ----
__global__ __launch_bounds__(1024) void k_scan(const int* __restrict__ deg,
    int* __restrict__ offs, int* __restrict__ cursor,
    float* __restrict__ lnum, float* __restrict__ lcnt)
{
  __shared__ int wsums[16];
  __shared__ int woffs[16];
  int tid = threadIdx.x, lane = tid & 63, wv = tid >> 6;
  if (tid < GG) { lnum[tid] = 0.0f; lcnt[tid] = 0.0f; }
  int base = tid * 20;
  int loc[20];
  int s = 0;
#pragma unroll
  for (int j = 0; j < 20; ++j) {
    int idx = base + j;
    int v = (idx < NN) ? deg[idx] : 0;
    loc[j] = s; s += v;
  }
  int inc = s;
  for (int o = 1; o < 64; o <<= 1) {
    int v = __shfl_up(inc, o, 64);
    if (lane >= o) inc += v;
  }
  if (lane == 63) wsums[wv] = inc;
  __syncthreads();
  if (wv == 0 && lane < 16) {
    int v = wsums[lane];
    int i2 = v;
    for (int o = 1; o < 16; o <<= 1) {
      int vv = __shfl_up(i2, o, 16);
      if (lane >= o) i2 += vv;
    }
    woffs[lane] = i2 - v;
  }
  __syncthreads();
  int texcl = woffs[wv] + (inc - s);
#pragma unroll
  for (int j = 0; j < 20; ++j) {
    int idx = base + j;
    if (idx < NN) { int v = texcl + loc[j]; offs[idx] = v; cursor[idx] = v; }
  }
  if (tid == 1023) offs[NN] = EE;
}

// ---------------- K4: edge geometry, written into receiver-sorted slots ------
__global__ __launch_bounds__(256) void k_edge2(
    const float* __restrict__ pos_noisy, const float* __restrict__ shifts,
    const int* __restrict__ ei, int* __restrict__ cursor,
    ushort_t* __restrict__ Ys, ushort_t* __restrict__ efs, int* __restrict__ snds)
{
  int e = blockIdx.x * 256 + threadIdx.x;  // EE exact
  int snd = ei[e], rcv = ei[EE + e];
  float vx = pos_noisy[rcv * 3 + 0] - pos_noisy[snd * 3 + 0] + shifts[e * 3 + 0];
  float vy = pos_noisy[rcv * 3 + 1] - pos_noisy[snd * 3 + 1] + shifts[e * 3 + 1];
  float vz = pos_noisy[rcv * 3 + 2] - pos_noisy[snd * 3 + 2] + shifts[e * 3 + 2];
  float r2 = vx * vx + vy * vy + vz * vz + 1e-12f;
  float r = sqrtf(r2);
  float inv = frcp(r);            // feeds bf16 outputs only
  float x = vx * inv, y = vy * inv, z = vz * inv;

  const float s3 = 1.7320508075688772f, s15 = 3.872983346207417f, s5 = 2.23606797749979f;
  const float s105 = 10.246950765959598f, s7 = 2.6457513110645907f;
  const float s35_8 = 2.091650066335189f, s21_8 = 1.6201851746019651f;
  float yv[16];
  yv[0] = 1.0f;
  yv[1] = s3 * x; yv[2] = s3 * y; yv[3] = s3 * z;
  yv[4] = s15 * x * y;
  yv[5] = s15 * y * z;
  yv[6] = 0.5f * s5 * (3.0f * z * z - 1.0f);
  yv[7] = s15 * x * z;
  yv[8] = 0.5f * s15 * (x * x - y * y);
  yv[9] = s35_8 * y * (3.0f * x * x - y * y);
  yv[10] = s105 * x * y * z;
  yv[11] = s21_8 * y * (5.0f * z * z - 1.0f);
  yv[12] = 0.5f * s7 * (5.0f * z * z * z - 3.0f * z);
  yv[13] = s21_8 * x * (5.0f * z * z - 1.0f);
  yv[14] = 0.5f * s105 * z * (x * x - y * y);
  yv[15] = s35_8 * x * (x * x - 3.0f * y * y);

  // radial embed: sqrt(2/5) * sin(n*pi*rc/5)/rc * poly_cutoff(r/5)
  float rc = fmaxf(r, 1e-9f);
  float pref = 0.6324555320336759f * frcp(rc);   // bf16 output -> fast rcp ok
  float th = 0.6283185307179586f * rc;
  float s1 = __sinf(th), c1 = __cosf(th);
  float xr = r * 0.2f;
  float fcut = 0.0f;
  if (xr < 1.0f) {
    float x2 = xr * xr, x3 = x2 * xr;
    float x6 = x3 * x3, x7 = x6 * xr, x8 = x7 * xr;
    fcut = 1.0f - 28.0f * x6 + 48.0f * x7 - 21.0f * x8;
  }
  float efv[8];
  float sp = 0.0f, scur = s1, c2 = 2.0f * c1;
#pragma unroll
  for (int b = 0; b < 8; ++b) {
    efv[b] = pref * scur * fcut;
    float nx = c2 * scur - sp;   // sin((n+1)th) = 2cos(th)sin(n th) - sin((n-1)th)
    sp = scur; scur = nx;
  }

  int slot = atomicAdd(&cursor[rcv], 1);
  snds[slot] = snd;
  uint4* Y4 = (uint4*)Ys;
  Y4[(size_t)slot * 2 + 0] = make_uint4(pk(yv[0], yv[1]), pk(yv[2], yv[3]),
                                        pk(yv[4], yv[5]), pk(yv[6], yv[7]));
  Y4[(size_t)slot * 2 + 1] = make_uint4(pk(yv[8], yv[9]), pk(yv[10], yv[11]),
                                        pk(yv[12], yv[13]), pk(yv[14], yv[15]));
  ((uint4*)efs)[slot] = make_uint4(pk(efv[0], efv[1]), pk(efv[2], efv[3]),
                                   pk(efv[4], efv[5]), pk(efv[6], efv[7]));
}

// ---------------- K4b: transpose Y into per-tile [k][e] layout ----------------
__global__ __launch_bounds__(256) void k_ytr(const ushort_t* __restrict__ Ys,
    ushort_t* __restrict__ YT)
{
  int idx = blockIdx.x * 256 + threadIdx.x;  // NTILE*16 = 320000 = 1250*256 exact
  int tile = idx >> 4, k = idx & 15;
  ushort_t v[16];
#pragma unroll
  for (int el = 0; el < 16; ++el)
    v[el] = Ys[(size_t)(tile * 16 + el) * 16 + k];
  uint_t u[8];
#pragma unroll
  for (int p = 0; p < 8; ++p) u[p] = (uint_t)v[2 * p] | ((uint_t)v[2 * p + 1] << 16);
  uint4* o = (uint4*)(YT + (size_t)tile * 256 + (size_t)k * 16);
  o[0] = make_uint4(u[0], u[1], u[2], u[3]);
  o[1] = make_uint4(u[4], u[5], u[6], u[7]);
}

// ---------------- K5: edge radial MLP via MFMA, ss folded, TRANSPOSED store --
// W2^T comes from global bf16 (w2tg) -> only h1 lives in LDS (36.9 KB, 4 blk/CU)
__global__ __launch_bounds__(256) void k_rw_mfma(
    const ushort_t* __restrict__ efs, const float* __restrict__ W_r1,
    const ushort_t* __restrict__ w2tg, const int* __restrict__ snds,
    const float* __restrict__ scal_in, ushort_t* __restrict__ rwT, int layer)
{
  __shared__ __align__(16) ushort_t h1[EPB][72];    // silu(ef@W1) bf16, padded
  int tid = threadIdx.x;
  const float* W1g = W_r1 + layer * NBB * HIDD;
  const ushort_t* w2l = w2tg + layer * (HIDD * 128);
  // h1 for this thread's edge (one edge per thread)
  {
    int e = blockIdx.x * EPB + tid;
    uint4 q = ((const uint4*)efs)[e];
    float efr[8] = {lo16(q.x), hi16(q.x), lo16(q.y), hi16(q.y),
                    lo16(q.z), hi16(q.z), lo16(q.w), hi16(q.w)};
    for (int hc = 0; hc < 8; ++hc) {
      float v[8];
#pragma unroll
      for (int hh = 0; hh < 8; ++hh) {
        int h = hc * 8 + hh;
        float t = 0.0f;
#pragma unroll
        for (int b = 0; b < 8; ++b) t = fmaf(efr[b], W1g[b * HIDD + h], t);
        v[hh] = t * frcp(1.0f + __expf(-t));   // silu, fast rcp (bf16 out)
      }
      *(uint4*)&h1[tid][hc * 8] = make_uint4(pk(v[0], v[1]), pk(v[2], v[3]),
                                             pk(v[4], v[5]), pk(v[6], v[7]));
    }
  }
  __builtin_amdgcn_wave_barrier();   // h1 rows are wave-private (64 rows per wave)
  int w = tid >> 6, lane = tid & 63;
  int c = lane & 15, quad = lane >> 4;
  // all 16 B-fragments (8 n-tiles x 2 k-tiles) from global bf16 (L1-hot, hoisted)
  bf16x8 bfr[16];
#pragma unroll
  for (int nt = 0; nt < 8; ++nt)
#pragma unroll
    for (int kt = 0; kt < 2; ++kt)
      bfr[nt * 2 + kt] = *(const bf16x8*)&w2l[(nt * 16 + c) * 64 + kt * 32 + quad * 8];
  int mb0 = w * 64;   // this wave covers 64 edges = 4 m-tiles
#pragma unroll
  for (int mt = 0; mt < 4; ++mt) {
    int mbase = mb0 + mt * 16;
    bf16x8 a0 = *(const bf16x8*)&h1[mbase + c][quad * 8];
    bf16x8 a1 = *(const bf16x8*)&h1[mbase + c][32 + quad * 8];
    size_t erow = (size_t)blockIdx.x * EPB + mbase + quad * 4;
    int4 sn = *(const int4*)&snds[erow];     // 4 consecutive edges' senders
    const float* sb0 = scal_in + (size_t)sn.x * CC;
    const float* sb1 = scal_in + (size_t)sn.y * CC;
    const float* sb2 = scal_in + (size_t)sn.z * CC;
    const float* sb3 = scal_in + (size_t)sn.w * CC;
    int tile = blockIdx.x * 16 + w * 4 + mt;  // global 16-slot tile index
#pragma unroll
    for (int nt = 0; nt < 8; ++nt) {
      f32x4 acc = {0.0f, 0.0f, 0.0f, 0.0f};
      acc = __builtin_amdgcn_mfma_f32_16x16x32_bf16(a0, bfr[nt * 2 + 0], acc, 0, 0, 0);
      acc = __builtin_amdgcn_mfma_f32_16x16x32_bf16(a1, bfr[nt * 2 + 1], acc, 0, 0, 0);
      int col = nt * 16 + c;
      int cc = col >> 2;                     // channel = col/4 (col = 4c+l)
      // C layout: acc[j] is edge (quad*4+j) of this tile, fixed col.
      uint2 st;
      st.x = pk(acc[0] * sb0[cc], acc[1] * sb1[cc]);
      st.y = pk(acc[2] * sb2[cc], acc[3] * sb3[cc]);
      *(uint2*)(rwT + (size_t)tile * 2048 + (size_t)col * 16 + quad * 4) = st;
    }
  }
}

// ---------------- K6: MFMA segment-aggregate + MFMA mix + poly + readout -----
// LDS: single aliased buffer lbuf holds agg[ch][k] then feats[d][k] (the agg
// data is fully consumed by the mix A-frag reads before feats is written;
// per-wave LDS is in-order and the wave executes in lockstep -> no race).
__global__ __launch_bounds__(256) void k_layer(
    const ushort_t* __restrict__ YT, const ushort_t* __restrict__ rwT,
    float* __restrict__ scal_out,
    const int* __restrict__ offs,
    const ushort_t* __restrict__ wmixb, const float* __restrict__ W_prod,
    const float* __restrict__ W_ro_s, const float* __restrict__ W_ro_v,
    const float* __restrict__ sc_skip, float* __restrict__ pred, int layer)
{
  __shared__ float lbuf[4][CC][17];    // 8.7 KB (aliased agg/feats), pad 17
  __shared__ float lf[4][CC][4];       // 2 KB
  int w = threadIdx.x >> 6, lane = threadIdx.x & 63;
  int n = blockIdx.x * 4 + w;        // NN = 5000*4 exactly
  int c = lane & 15, quad = lane >> 4;
  int i0 = offs[n], i1 = offs[n + 1];
  int t0 = i0 >> 4, t1 = (i1 + 15) >> 4;   // tiles overlapping this node
  int tsel = quad >> 1, half8 = quad & 1;
  f32x4 acc[8];
#pragma unroll
  for (int mt = 0; mt < 8; ++mt) acc[mt] = (f32x4){0.0f, 0.0f, 0.0f, 0.0f};

  for (int t = t0; t < t1; t += 2) {       // K = 32 edges per step (2 tiles)
    int ta = t + tsel;                      // quad pair 0/1 -> tile t, 2/3 -> t+1
    bf16x8 a[8];
    bf16x8 b;
    int sbase = ta * 16 + half8 * 8;
    // this quad-half contributes iff its 8-slot range intersects the segment
    bool av = (sbase < i1) && (sbase + 8 > i0) && (ta < t1);
    if (av) {
      const bf16x8* ap = (const bf16x8*)rwT + (size_t)ta * 256 + c * 2 + half8;
#pragma unroll
      for (int mt = 0; mt < 8; ++mt) a[mt] = ap[mt * 32];
      b = ((const bf16x8*)YT)[(size_t)ta * 32 + c * 2 + half8];
      if (sbase < i0 || sbase + 8 > i1) {
#pragma unroll
        for (int j = 0; j < 8; ++j) {
          int s = sbase + j;
          if (s < i0 || s >= i1) b[j] = 0;   // zero Y outside segment -> 0 contrib
        }
      }
    } else {
#pragma unroll
      for (int mt = 0; mt < 8; ++mt) a[mt] = (bf16x8){0, 0, 0, 0, 0, 0, 0, 0};
      b = (bf16x8){0, 0, 0, 0, 0, 0, 0, 0};
    }
#pragma unroll
    for (int mt = 0; mt < 8; ++mt)
      acc[mt] = __builtin_amdgcn_mfma_f32_16x16x32_bf16(a[mt], b, acc[mt], 0, 0, 0);
  }

  // C layout: acc[mt][j] = agg_full[row = mt*16 + quad*4 + j][k = c]
  //   -> channel = mt*4 + quad, kk = j; select j = L_OF_LM[c]
  int lc = (c >= 1) + (c >= 4) + (c >= 9);
  const float inva = 1.0f / 16.0f;
#pragma unroll
  for (int mt = 0; mt < 8; ++mt) {
    float v = (lc == 0) ? acc[mt][0] : (lc == 1) ? acc[mt][1]
            : (lc == 2) ? acc[mt][2] : acc[mt][3];
    lbuf[w][mt * 4 + quad][c] = v * inva;    // agg[ch][k]
  }
  __builtin_amdgcn_wave_barrier();

  // ---- mix via MFMA: out[k][lq*32+d] = sum_ch agg[ch][k] * Wm[lq][ch][d] ----
  float av2[8];
#pragma unroll
  for (int j = 0; j < 8; ++j) av2[j] = lbuf[w][quad * 8 + j][c];
  __builtin_amdgcn_wave_barrier();   // all agg reads precede feats writes below
  union { uint_t u[4]; bf16x8 b; } cv;
  cv.u[0] = pk(av2[0], av2[1]); cv.u[1] = pk(av2[2], av2[3]);
  cv.u[2] = pk(av2[4], av2[5]); cv.u[3] = pk(av2[6], av2[7]);
  bf16x8 afrag = cv.b;
  const ushort_t* wmixl = wmixb + layer * 4096;
  f32x4 o[8];
#pragma unroll
  for (int nt = 0; nt < 8; ++nt) {
    bf16x8 bfm = *(const bf16x8*)&wmixl[(nt * 16 + c) * 32 + quad * 8];
    f32x4 z = {0.0f, 0.0f, 0.0f, 0.0f};
    o[nt] = __builtin_amdgcn_mfma_f32_16x16x32_bf16(afrag, bfm, z, 0, 0, 0);
  }
  // C layout: o[nt][jj] = out[row=k=quad*4+jj][col=nt*16+c]; lq(col)=nt>>1,
  // d = (nt&1)*16 + c. Keep only cols whose lq == L_OF_LM[k].
#pragma unroll
  for (int jj = 0; jj < 4; ++jj) {
    int k = quad * 4 + jj;
    int lq = (k >= 1) + (k >= 4) + (k >= 9);
    float vlo = (lq == 0) ? o[0][jj] : (lq == 1) ? o[2][jj]
              : (lq == 2) ? o[4][jj] : o[6][jj];
    float vhi = (lq == 0) ? o[1][jj] : (lq == 1) ? o[3][jj]
              : (lq == 2) ? o[5][jj] : o[7][jj];
    lbuf[w][c][k] = vlo;                 // feats[d][k] (aliases dead agg data)
    lbuf[w][c + 16][k] = vhi;
  }
  __builtin_amdgcn_wave_barrier();

  // ---- epilogue: poly + skip ----
  int d = lane >> 1;
  int kh = lane & 1;
  int kb = kh * 8;
  float ft[8];
#pragma unroll
  for (int j = 0; j < 8; ++j) ft[j] = lbuf[w][d][kb + j];
  float sv = lbuf[w][d][0];                // k=0 (pre-poly)
  const float* Wp = W_prod + layer * 96;
  float p0 = Wp[d], p1 = Wp[32 + d], p2 = Wp[64 + d];
  float poly = fmaf(fmaf(p2, sv, p1), sv, p0);
#pragma unroll
  for (int j = 0; j < 8; ++j) ft[j] *= poly;
  if (layer == 0 && kh == 0) ft[0] += sc_skip[n * CC + d];
  if (kh == 0) {
    scal_out[n * CC + d] = ft[0];
    lf[w][d][0] = ft[0]; lf[w][d][1] = ft[1]; lf[w][d][2] = ft[2]; lf[w][d][3] = ft[3];
  }
  __builtin_amdgcn_wave_barrier();
  // all-lane readout: part p = lane>>4 sums dd in [p*8, p*8+8), 2-step reduce
  {
    int p = lane >> 4, m = lane & 15;
    float sum = 0.0f;
    if (m < 13) {
      if (m < 10) {
        const float* Wr = W_ro_s + layer * CC * NEL;
#pragma unroll
        for (int q = 0; q < 8; ++q) {
          int dd = p * 8 + q;
          sum = fmaf(lf[w][dd][0], Wr[dd * NEL + m], sum);
        }
      } else {
        int mm = m - 10;
        const float* Wv = W_ro_v + layer * CC;
#pragma unroll
        for (int q = 0; q < 8; ++q) {
          int dd = p * 8 + q;
          sum = fmaf(lf[w][dd][1 + mm], Wv[dd], sum);
        }
      }
    }
    sum += __shfl_down(sum, 32, 64);
    sum += __shfl_down(sum, 16, 64);
    if (lane < 13) pred[n * 13 + lane] += sum;
  }
}

// ---------------- K7: loss accumulation (hierarchical: LDS -> global) --------
__global__ __launch_bounds__(256) void k_loss(const float* __restrict__ pred,
    const float* __restrict__ eps, const int* __restrict__ batch,
    float* __restrict__ lnum, float* __restrict__ lcnt)
{
  __shared__ float psum[GG];
  __shared__ int pcnt[GG];
  int tid = threadIdx.x;
  if (tid < GG) { psum[tid] = 0.0f; pcnt[tid] = 0; }
  __syncthreads();
  int n = blockIdx.x * 256 + tid;
  if (n < NN) {
    int g = batch[n];
    float sum = 0.0f;
#pragma unroll
    for (int j = 0; j < 13; ++j) {
      float dlt = pred[n * 13 + j] - eps[n * 13 + j];
      sum = fmaf(dlt, dlt, sum);
    }
    atomicAdd(&psum[g], sum);   // LDS atomic; batch sorted -> 1-2 distinct g per block
    atomicAdd(&pcnt[g], 1);
  }
  __syncthreads();
  if (tid < GG && pcnt[tid] > 0) {
    atomicAdd(&lnum[tid], psum[tid]);
    atomicAdd(&lcnt[tid], (float)pcnt[tid]);
  }
}

__global__ void k_final(const float* __restrict__ lnum, const float* __restrict__ lcnt,
    float* __restrict__ out)
{
  int g = threadIdx.x;
  if (g < GG) {
    float nn = fmaxf(lcnt[g], 1.0f);
    out[g] = 0.5f * lnum[g] / (nn * 13.0f);
  }
}

extern "C" void kernel_launch(void* const* d_in, const int* in_sizes, int n_in,
                              void* d_out, int out_size, void* d_ws, size_t ws_size,
                              hipStream_t stream) {
  const float* positions  = (const float*)d_in[0];
  const float* node_attrs = (const float*)d_in[1];
  const float* shifts     = (const float*)d_in[2];
  const float* eps        = (const float*)d_in[3];
  const float* alpha_bar  = (const float*)d_in[4];
  const float* W_embed    = (const float*)d_in[5];
  const float* W_r1       = (const float*)d_in[6];
  const float* W_r2       = (const float*)d_in[7];
  const float* W_mix      = (const float*)d_in[8];
  const float* W_sc       = (const float*)d_in[9];
  const float* W_prod     = (const float*)d_in[10];
  const float* W_ro_s     = (const float*)d_in[11];
  const float* W_ro_v     = (const float*)d_in[12];
  const int* edge_index   = (const int*)d_in[13];
  const int* batch        = (const int*)d_in[14];
  const int* tarr         = (const int*)d_in[15];
  float* out = (float*)d_out;

  char* ws = (char*)d_ws;
  size_t off = 0;
  auto alloc = [&](size_t bytes) -> void* {
    void* p = ws + off;
    off = (off + bytes + 255) & ~(size_t)255;
    return p;
  };
  // total ~107 MB (ws_size = 256 MiB)
  float* pos_noisy = (float*)alloc(NN * 3 * 4);
  float* scalA     = (float*)alloc(NN * CC * 4);
  float* scalB     = (float*)alloc(NN * CC * 4);
  float* sc_skip   = (float*)alloc(NN * CC * 4);
  float* pred      = (float*)alloc(NN * 13 * 4);
  ushort_t* Ys     = (ushort_t*)alloc((size_t)EE * 16 * 2);       // sorted, bf16 [slot][k]
  ushort_t* YT     = (ushort_t*)alloc((size_t)EE * 16 * 2);       // per-tile [k][e]
  ushort_t* efs    = (ushort_t*)alloc((size_t)EE * 8 * 2);        // sorted, bf16
  int* snds        = (int*)alloc((size_t)EE * 4);                 // sorted sender ids
  ushort_t* rwT    = (ushort_t*)alloc((size_t)EE * 128 * 2);      // rw*ss, per-tile [col][e]
  ushort_t* w2tg   = (ushort_t*)alloc(2 * HIDD * 128 * 2);        // W2^T bf16, both layers
  ushort_t* wmixb  = (ushort_t*)alloc(2 * 128 * CC * 2);          // Wmix packed, both layers
  int* deg         = (int*)alloc(NN * 4);
  int* offs        = (int*)alloc((NN + 1) * 4);
  int* cursor      = (int*)alloc(NN * 4);
  float* lnum      = (float*)alloc(GG * 4);
  float* lcnt      = (float*)alloc(GG * 4);
  (void)ws_size; (void)in_sizes; (void)n_in; (void)out_size;

  const int NB_N = (NN + 255) / 256;   // 79
  const int NB_E = EE / 256;           // 1250

  k_prep<<<NB_N + 96, 256, 0, stream>>>(positions, node_attrs, eps, alpha_bar,
                                        W_embed, W_sc, W_r2, W_mix, batch, tarr,
                                        pos_noisy, scalA, sc_skip, pred, deg,
                                        w2tg, wmixb);
  k_edge_deg<<<NB_E, 256, 0, stream>>>(edge_index, deg);
  k_scan<<<1, 1024, 0, stream>>>(deg, offs, cursor, lnum, lcnt);
  k_edge2<<<NB_E, 256, 0, stream>>>(pos_noisy, shifts, edge_index, cursor, Ys, efs, snds);
  k_ytr<<<NB_E, 256, 0, stream>>>(Ys, YT);   // NTILE*16/256 = 1250 blocks exact

  for (int layer = 0; layer < 2; ++layer) {
    const float* sin_p = (layer == 0) ? scalA : scalB;
    float* sout_p      = (layer == 0) ? scalB : scalA;
    k_rw_mfma<<<NB_E, 256, 0, stream>>>(efs, W_r1, w2tg, snds, sin_p, rwT, layer);
    k_layer<<<NN / 4, 256, 0, stream>>>(YT, rwT, sout_p, offs,
                                        wmixb, W_prod, W_ro_s, W_ro_v,
                                        sc_skip, pred, layer);
  }

  k_loss<<<NB_N, 256, 0, stream>>>(pred, eps, batch, lnum, lcnt);
  k_final<<<1, 64, 0, stream>>>(lnum, lcnt, out);
}